// Round 2
// baseline (840.301 us; speedup 1.0000x reference)
//
#include <hip/hip_runtime.h>
#include <stdint.h>

typedef __attribute__((ext_vector_type(8))) short short8;
typedef __attribute__((ext_vector_type(4))) float floatx4;
typedef unsigned short ushort_t;

#define E_TOTAL 640000
#define M_BLK   128
#define N_TILES (E_TOTAL / M_BLK)   // 5000
#define GRID_P  512                 // 2 persistent blocks per CU
#define XS_LD   264   // 256 + 8 fp16 pad -> row stride 528B (16B aligned)
#define HS_LD   136   // 128 + 8 fp16 pad -> row stride 272B (16B aligned)

__device__ __forceinline__ unsigned short f2h(float f){
    _Float16 h = (_Float16)f;                  // v_cvt_f16_f32, RNE
    union { _Float16 h; unsigned short u; } v; v.h = h; return v.u;
}
__device__ __forceinline__ unsigned pk2h(float a, float b){
    return (unsigned)f2h(a) | ((unsigned)f2h(b) << 16);
}

// Repack W1[256,128] / W2[128,64] (row-major fp32) into fp16 MFMA B-fragment
// order: lane's 8 B-elements contiguous (one 16B load).
__global__ void repack_w(const float* __restrict__ W1,
                         const float* __restrict__ W2,
                         ushort_t* __restrict__ W1p,
                         ushort_t* __restrict__ W2p){
    int tid = blockIdx.x * 256 + threadIdx.x;
    if (tid < 8*8*64){
        int kt = tid >> 9, nt = (tid >> 6) & 7, l = tid & 63;
        int q = l >> 4, c = l & 15;
        ushort_t tmp[8];
        #pragma unroll
        for (int j = 0; j < 8; j++)
            tmp[j] = f2h(W1[(kt*32 + q*8 + j)*128 + nt*16 + c]);
        #pragma unroll
        for (int j = 0; j < 8; j++) W1p[tid*8 + j] = tmp[j];
    } else if (tid < 8*8*64 + 4*4*64){
        int t = tid - 8*8*64;
        int kt = t >> 8, nt = (t >> 6) & 3, l = t & 63;
        int q = l >> 4, c = l & 15;
        ushort_t tmp[8];
        #pragma unroll
        for (int j = 0; j < 8; j++)
            tmp[j] = f2h(W2[(kt*32 + q*8 + j)*64 + nt*16 + c]);
        #pragma unroll
        for (int j = 0; j < 8; j++) W2p[t*8 + j] = tmp[j];
    }
}

// Persistent, software-pipelined: each block walks tiles bid, bid+512, ...
// Gathers for tile t+1 are issued while GEMMs of tile t run; conversions are
// moved out of the barrier-critical LDS-write window.
__global__ __launch_bounds__(512, 4)
void edge_mlp(const float* __restrict__ node_attr,
              const float* __restrict__ edge_attr,
              const float* __restrict__ global_attr,
              const float* __restrict__ node_mask,
              const float* __restrict__ edge_mask,
              const int*   __restrict__ edge_index,
              const int*   __restrict__ eg_index,
              const float* __restrict__ b1,
              const float* __restrict__ b2,
              const ushort_t* __restrict__ W1p,
              const ushort_t* __restrict__ W2p,
              float*       __restrict__ out){
    __shared__ ushort_t Xs[M_BLK * XS_LD];   // re-used as Hs after barrier
    ushort_t* Hs = Xs;                        // [M_BLK][HS_LD] overlay

    const int tid  = threadIdx.x;
    const int w    = tid >> 6, lane = tid & 63;
    const int q    = lane >> 4, cc = lane & 15;
    const int mt0  = (w >> 2) * 4;   // GEMM1: wave owns 4mt x 2nt
    const int nt0  = (w & 3) * 2;
    const int mt20 = (w >> 1) * 2;   // GEMM2: wave owns 2mt x 2nt
    const int nt20 = (w & 1) * 2;

    // node-gather role: thread handles half a node row
    const int nr = tid >> 2, nseg = (tid >> 1) & 1, nhalf = tid & 1;

    // hoisted biases
    float bb1v[2], bb2v[2];
    #pragma unroll
    for (int j = 0; j < 2; j++){
        bb1v[j] = b1[(nt0  + j)*16 + cc];
        bb2v[j] = b2[(nt20 + j)*16 + cc];
    }

    const short8* W1v = (const short8*)W1p;
    const short8* W2v = (const short8*)W2p;

    int t = blockIdx.x;

    // pipeline registers (packed fp16, ready to write to LDS)
    uint2 pn16[8];            // masked node half-row  (tile t)
    uint2 pe16[4];            // edge_attr quarters    (tile t)
    uint2 pg16[4];            // global quarters       (tile t)
    int   ei_n;               // edge index for tile t+GRID_P
    int   eg_n[4];            // graph indices for tile t+GRID_P

    // -------- prologue: fetch + convert tile t; prefetch indices t+1 --------
    {
        size_t e0 = (size_t)t * M_BLK;
        int ei = edge_index[nseg*E_TOTAL + e0 + nr];
        int eg[4];
        #pragma unroll
        for (int k = 0; k < 4; k++) eg[k] = eg_index[e0 + ((tid + k*512) >> 4)];
        float nm = node_mask[ei];
        const floatx4* nsrc = (const floatx4*)(node_attr + (size_t)ei*64) + nhalf*8;
        floatx4 nraw[8], eraw[4], graw[4];
        #pragma unroll
        for (int c2 = 0; c2 < 8; c2++) nraw[c2] = nsrc[c2];
        const floatx4* esrc = (const floatx4*)(edge_attr + e0*64);
        #pragma unroll
        for (int k = 0; k < 4; k++) eraw[k] = esrc[tid + k*512];
        #pragma unroll
        for (int k = 0; k < 4; k++)
            graw[k] = ((const floatx4*)(global_attr + (size_t)eg[k]*64))[(tid + k*512) & 15];
        #pragma unroll
        for (int c2 = 0; c2 < 8; c2++){
            pn16[c2].x = pk2h(nraw[c2].x*nm, nraw[c2].y*nm);
            pn16[c2].y = pk2h(nraw[c2].z*nm, nraw[c2].w*nm);
        }
        #pragma unroll
        for (int k = 0; k < 4; k++){
            pe16[k].x = pk2h(eraw[k].x, eraw[k].y); pe16[k].y = pk2h(eraw[k].z, eraw[k].w);
            pg16[k].x = pk2h(graw[k].x, graw[k].y); pg16[k].y = pk2h(graw[k].z, graw[k].w);
        }
    }
    ei_n = 0; eg_n[0] = eg_n[1] = eg_n[2] = eg_n[3] = 0;
    if (t + GRID_P < N_TILES){
        size_t e0n = (size_t)(t + GRID_P) * M_BLK;
        ei_n = edge_index[nseg*E_TOTAL + e0n + nr];
        #pragma unroll
        for (int k = 0; k < 4; k++) eg_n[k] = eg_index[e0n + ((tid + k*512) >> 4)];
    }

    for (; t < N_TILES; t += GRID_P){
        const size_t e0 = (size_t)t * M_BLK;
        const bool hn  = (t +   GRID_P < N_TILES);
        const bool hn2 = (t + 2*GRID_P < N_TILES);

        __syncthreads();   // previous iteration's Hs reads complete

        // ---- LDS write: X tile (pure stores, data pre-packed) ----
        {
            ushort_t* dst = &Xs[nr*XS_LD + 64 + nseg*64 + nhalf*32];
            #pragma unroll
            for (int c2 = 0; c2 < 8; c2++) *(uint2*)(dst + c2*4) = pn16[c2];
        }
        #pragma unroll
        for (int k = 0; k < 4; k++){
            int idx = tid + k*512; int r = idx >> 4, c = idx & 15;
            *(uint2*)&Xs[r*XS_LD + c*4]       = pe16[k];
            *(uint2*)&Xs[r*XS_LD + 192 + c*4] = pg16[k];
        }
        __syncthreads();

        // ---- issue: node gathers for t+1 (indices already resident),
        //             index loads for t+2 ----
        float nm_n = 0.f;
        floatx4 nraw[8];
        if (hn){
            nm_n = node_mask[ei_n];
            const floatx4* nsrc = (const floatx4*)(node_attr + (size_t)ei_n*64) + nhalf*8;
            #pragma unroll
            for (int c2 = 0; c2 < 8; c2++) nraw[c2] = nsrc[c2];
        }
        int ei_n2 = 0, eg_n2[4] = {0,0,0,0};
        if (hn2){
            size_t e0n2 = (size_t)(t + 2*GRID_P) * M_BLK;
            ei_n2 = edge_index[nseg*E_TOTAL + e0n2 + nr];
            #pragma unroll
            for (int k = 0; k < 4; k++) eg_n2[k] = eg_index[e0n2 + ((tid + k*512) >> 4)];
        }

        // ---- GEMM1: H[128,128] = X[128,256] @ W1 (hides node-gather latency) ----
        floatx4 acc[4][2];
        #pragma unroll
        for (int i = 0; i < 4; i++)
            #pragma unroll
            for (int j = 0; j < 2; j++) acc[i][j] = (floatx4){0.f,0.f,0.f,0.f};

        #pragma unroll
        for (int kt = 0; kt < 8; kt++){
            short8 b[2];
            #pragma unroll
            for (int j = 0; j < 2; j++) b[j] = W1v[(kt*8 + nt0 + j)*64 + lane];
            #pragma unroll
            for (int i = 0; i < 4; i++){
                const short8 a = *(const short8*)&Xs[((mt0 + i)*16 + cc)*XS_LD + kt*32 + q*8];
                #pragma unroll
                for (int j = 0; j < 2; j++)
                    acc[i][j] = __builtin_amdgcn_mfma_f32_16x16x32_f16(a, b[j], acc[i][j], 0, 0, 0);
            }
        }

        // ---- convert node (t+1) to packed fp16; issue edge/global loads (t+1)
        //      (their latency hides under epi1 + GEMM2 + epi2) ----
        floatx4 eraw[4], graw[4];
        if (hn){
            #pragma unroll
            for (int c2 = 0; c2 < 8; c2++){
                pn16[c2].x = pk2h(nraw[c2].x*nm_n, nraw[c2].y*nm_n);
                pn16[c2].y = pk2h(nraw[c2].z*nm_n, nraw[c2].w*nm_n);
            }
            size_t e0n = (size_t)(t + GRID_P) * M_BLK;
            const floatx4* esrc = (const floatx4*)(edge_attr + e0n*64);
            #pragma unroll
            for (int k = 0; k < 4; k++) eraw[k] = esrc[tid + k*512];
            #pragma unroll
            for (int k = 0; k < 4; k++)
                graw[k] = ((const floatx4*)(global_attr + (size_t)eg_n[k]*64))[(tid + k*512) & 15];
        }

        __syncthreads();   // everyone done reading Xs before Hs overlay

        // ---- epilogue 1: +b1, relu, fp16 -> Hs ----
        #pragma unroll
        for (int j = 0; j < 2; j++){
            int col = (nt0 + j)*16 + cc;
            #pragma unroll
            for (int i = 0; i < 4; i++){
                int rowb = (mt0 + i)*16 + q*4;
                #pragma unroll
                for (int r = 0; r < 4; r++){
                    float v = acc[i][j][r] + bb1v[j];
                    v = v > 0.f ? v : 0.f;
                    Hs[(rowb + r)*HS_LD + col] = f2h(v);
                }
            }
        }
        __syncthreads();

        // ---- GEMM2: OUT[128,64] = H[128,128] @ W2 ----
        floatx4 acc2[2][2];
        #pragma unroll
        for (int i = 0; i < 2; i++)
            #pragma unroll
            for (int j = 0; j < 2; j++) acc2[i][j] = (floatx4){0.f,0.f,0.f,0.f};

        #pragma unroll
        for (int kt = 0; kt < 4; kt++){
            short8 b[2];
            #pragma unroll
            for (int j = 0; j < 2; j++) b[j] = W2v[(kt*4 + nt20 + j)*64 + lane];
            #pragma unroll
            for (int i = 0; i < 2; i++){
                const short8 a = *(const short8*)&Hs[((mt20 + i)*16 + cc)*HS_LD + kt*32 + q*8];
                #pragma unroll
                for (int j = 0; j < 2; j++)
                    acc2[i][j] = __builtin_amdgcn_mfma_f32_16x16x32_f16(a, b[j], acc2[i][j], 0, 0, 0);
            }
        }

        // ---- epilogue 2: +b2, *edge_mask, store fp32 ----
        #pragma unroll
        for (int i = 0; i < 2; i++){
            #pragma unroll
            for (int r = 0; r < 4; r++){
                int row = (mt20 + i)*16 + q*4 + r;
                float em = edge_mask[e0 + row];
                size_t base = (size_t)(e0 + row) * 64;
                #pragma unroll
                for (int j = 0; j < 2; j++)
                    out[base + (nt20 + j)*16 + cc] = (acc2[i][j][r] + bb2v[j]) * em;
            }
        }

        // ---- pack edge/global (t+1) outside the barrier-critical window ----
        if (hn){
            #pragma unroll
            for (int k = 0; k < 4; k++){
                pe16[k].x = pk2h(eraw[k].x, eraw[k].y); pe16[k].y = pk2h(eraw[k].z, eraw[k].w);
                pg16[k].x = pk2h(graw[k].x, graw[k].y); pg16[k].y = pk2h(graw[k].z, graw[k].w);
            }
        }
        ei_n = ei_n2;
        #pragma unroll
        for (int k = 0; k < 4; k++) eg_n[k] = eg_n2[k];
    }
}

extern "C" void kernel_launch(void* const* d_in, const int* in_sizes, int n_in,
                              void* d_out, int out_size, void* d_ws, size_t ws_size,
                              hipStream_t stream){
    const float* node_attr   = (const float*)d_in[0];
    const float* edge_attr   = (const float*)d_in[1];
    const float* global_attr = (const float*)d_in[2];
    const float* node_mask   = (const float*)d_in[3];
    const float* edge_mask   = (const float*)d_in[4];
    const int*   edge_index  = (const int*)d_in[5];
    const int*   eg_index    = (const int*)d_in[6];
    const float* W1          = (const float*)d_in[7];
    const float* b1          = (const float*)d_in[8];
    const float* W2          = (const float*)d_in[9];
    const float* b2          = (const float*)d_in[10];

    ushort_t* W1p = (ushort_t*)d_ws;            // 8*8*64*8 = 32768 elems (64 KB)
    ushort_t* W2p = W1p + 8*8*64*8;             // 4*4*64*8 =  8192 elems (16 KB)

    repack_w<<<20, 256, 0, stream>>>(W1, W2, W1p, W2p);
    edge_mlp<<<GRID_P, 512, 0, stream>>>(
        node_attr, edge_attr, global_attr, node_mask, edge_mask,
        edge_index, eg_index, b1, b2, W1p, W2p, (float*)d_out);
}

// Round 3
// 429.744 us; speedup vs baseline: 1.9554x; 1.9554x over previous
//
#include <hip/hip_runtime.h>
#include <stdint.h>

typedef __attribute__((ext_vector_type(8))) short short8;
typedef __attribute__((ext_vector_type(4))) float floatx4;
typedef unsigned short ushort_t;

#define E_TOTAL 640000
#define M_BLK   64
#define N_TILES (E_TOTAL / M_BLK)   // 10000
#define XS_LD   264   // 256 + 8 fp16 pad -> row stride 528B (16B aligned)
#define HS_LD   136   // 128 + 8 fp16 pad -> row stride 272B (16B aligned)

__device__ __forceinline__ unsigned short f2h(float f){
    _Float16 h = (_Float16)f;                  // v_cvt_f16_f32, RNE
    union { _Float16 h; unsigned short u; } v; v.h = h; return v.u;
}
__device__ __forceinline__ unsigned pk2h(float a, float b){
    return (unsigned)f2h(a) | ((unsigned)f2h(b) << 16);
}

// Repack W1[256,128] / W2[128,64] (row-major fp32) into fp16 MFMA B-fragment
// order: lane's 8 B-elements contiguous (one 16B load).
__global__ void repack_w(const float* __restrict__ W1,
                         const float* __restrict__ W2,
                         ushort_t* __restrict__ W1p,
                         ushort_t* __restrict__ W2p){
    int tid = blockIdx.x * 256 + threadIdx.x;
    if (tid < 8*8*64){
        int kt = tid >> 9, nt = (tid >> 6) & 7, l = tid & 63;
        int q = l >> 4, c = l & 15;
        ushort_t tmp[8];
        #pragma unroll
        for (int j = 0; j < 8; j++)
            tmp[j] = f2h(W1[(kt*32 + q*8 + j)*128 + nt*16 + c]);
        #pragma unroll
        for (int j = 0; j < 8; j++) W1p[tid*8 + j] = tmp[j];
    } else if (tid < 8*8*64 + 4*4*64){
        int t = tid - 8*8*64;
        int kt = t >> 8, nt = (t >> 6) & 3, l = t & 63;
        int q = l >> 4, c = l & 15;
        ushort_t tmp[8];
        #pragma unroll
        for (int j = 0; j < 8; j++)
            tmp[j] = f2h(W2[(kt*32 + q*8 + j)*64 + nt*16 + c]);
        #pragma unroll
        for (int j = 0; j < 8; j++) W2p[t*8 + j] = tmp[j];
    }
}

// M_BLK=64, 512 threads (8 waves), LDS 33.8 KB -> 4 blocks/CU = 32 waves/CU
// (full occupancy). No cross-tile pipeline state => no spill. Overlap comes
// from 4 independently-phased blocks per CU.
__global__ __launch_bounds__(512, 8)
void edge_mlp(const float* __restrict__ node_attr,
              const float* __restrict__ edge_attr,
              const float* __restrict__ global_attr,
              const float* __restrict__ node_mask,
              const float* __restrict__ edge_mask,
              const int*   __restrict__ edge_index,
              const int*   __restrict__ eg_index,
              const float* __restrict__ b1,
              const float* __restrict__ b2,
              const ushort_t* __restrict__ W1p,
              const ushort_t* __restrict__ W2p,
              float*       __restrict__ out){
    __shared__ ushort_t Xs[M_BLK * XS_LD];   // re-used as Hs after barrier
    ushort_t* Hs = Xs;                        // [M_BLK][HS_LD] overlay

    const int tid = threadIdx.x;
    const int e0  = blockIdx.x * M_BLK;

    // ---- seg0: edge_attr rows (fp32), coalesced float4, cvt->fp16 ----
    {
        const float4* src = (const float4*)(edge_attr + (size_t)e0 * 64);
        #pragma unroll
        for (int k = 0; k < 2; k++){
            int idx = tid + k*512;            // 0..1023 ; 16 float4 per row
            int r = idx >> 4, c = idx & 15;
            float4 v = src[idx];
            uint2 o; o.x = pk2h(v.x, v.y); o.y = pk2h(v.z, v.w);
            *(uint2*)&Xs[r*XS_LD + c*4] = o;
        }
    }
    // ---- seg3: global gather (16 distinct rows, L2-hot) ----
    {
        #pragma unroll
        for (int k = 0; k < 2; k++){
            int idx = tid + k*512; int r = idx >> 4, c = idx & 15;
            int g = eg_index[e0 + r];
            const float4* src = (const float4*)(global_attr + (size_t)g * 64);
            float4 v = src[c];
            uint2 o; o.x = pk2h(v.x, v.y); o.y = pk2h(v.z, v.w);
            *(uint2*)&Xs[r*XS_LD + 192 + c*4] = o;
        }
    }
    // ---- seg1/seg2: node gathers with node_mask scaling ----
    // 8 threads per edge row: (seg, quarter) each thread does 4 float4.
    {
        int r = tid >> 3, seg = (tid >> 2) & 1, nq = tid & 3;
        int idx = edge_index[seg*E_TOTAL + e0 + r];
        float m = node_mask[idx];
        const float4* src = (const float4*)(node_attr + (size_t)idx * 64) + nq*4;
        ushort_t* dst = &Xs[r*XS_LD + 64 + seg*64 + nq*16];
        #pragma unroll
        for (int c2 = 0; c2 < 4; c2++){
            float4 v = src[c2];
            uint2 o; o.x = pk2h(v.x*m, v.y*m); o.y = pk2h(v.z*m, v.w*m);
            *(uint2*)(dst + c2*4) = o;
        }
    }
    __syncthreads();

    // ---- GEMM1: H[64,128] = X[64,256] @ W1 ; wave owns 1mt x 4nt ----
    const int w  = tid >> 6, lane = tid & 63;
    const int q  = lane >> 4, cc = lane & 15;
    const int mtw = w >> 1;          // 0..3
    const int nt0 = (w & 1) * 4;     // 0 or 4

    floatx4 acc[4];
    #pragma unroll
    for (int j = 0; j < 4; j++) acc[j] = (floatx4){0.f,0.f,0.f,0.f};

    const short8* W1v = (const short8*)W1p;
    #pragma unroll
    for (int kt = 0; kt < 8; kt++){
        short8 b[4];
        #pragma unroll
        for (int j = 0; j < 4; j++) b[j] = W1v[(kt*8 + nt0 + j)*64 + lane];
        const short8 a = *(const short8*)&Xs[(mtw*16 + cc)*XS_LD + kt*32 + q*8];
        #pragma unroll
        for (int j = 0; j < 4; j++)
            acc[j] = __builtin_amdgcn_mfma_f32_16x16x32_f16(a, b[j], acc[j], 0, 0, 0);
    }
    __syncthreads();   // everyone done reading Xs before Hs overlay

    // ---- epilogue 1: +b1, relu, fp16 -> Hs (row-major) ----
    #pragma unroll
    for (int j = 0; j < 4; j++){
        int col = (nt0 + j)*16 + cc;
        float bb = b1[col];
        int rowb = mtw*16 + q*4;
        #pragma unroll
        for (int r = 0; r < 4; r++){
            float v = acc[j][r] + bb;
            v = v > 0.f ? v : 0.f;
            Hs[(rowb + r)*HS_LD + col] = f2h(v);
        }
    }
    __syncthreads();

    // ---- GEMM2: OUT[64,64] = H[64,128] @ W2 ; wave owns 1mt x 2nt ----
    const int mt2  = w >> 1;         // 0..3
    const int nt20 = (w & 1) * 2;    // 0 or 2

    floatx4 acc2[2];
    #pragma unroll
    for (int j = 0; j < 2; j++) acc2[j] = (floatx4){0.f,0.f,0.f,0.f};

    const short8* W2v = (const short8*)W2p;
    #pragma unroll
    for (int kt = 0; kt < 4; kt++){
        short8 b[2];
        #pragma unroll
        for (int j = 0; j < 2; j++) b[j] = W2v[(kt*4 + nt20 + j)*64 + lane];
        const short8 a = *(const short8*)&Hs[(mt2*16 + cc)*HS_LD + kt*32 + q*8];
        #pragma unroll
        for (int j = 0; j < 2; j++)
            acc2[j] = __builtin_amdgcn_mfma_f32_16x16x32_f16(a, b[j], acc2[j], 0, 0, 0);
    }

    // ---- epilogue 2: +b2, *edge_mask, store fp32 ----
    float bb2[2];
    #pragma unroll
    for (int j = 0; j < 2; j++) bb2[j] = b2[(nt20 + j)*16 + cc];
    #pragma unroll
    for (int r = 0; r < 4; r++){
        int row = mt2*16 + q*4 + r;
        float em = edge_mask[e0 + row];
        size_t base = (size_t)(e0 + row) * 64;
        #pragma unroll
        for (int j = 0; j < 2; j++)
            out[base + (nt20 + j)*16 + cc] = (acc2[j][r] + bb2[j]) * em;
    }
}

extern "C" void kernel_launch(void* const* d_in, const int* in_sizes, int n_in,
                              void* d_out, int out_size, void* d_ws, size_t ws_size,
                              hipStream_t stream){
    const float* node_attr   = (const float*)d_in[0];
    const float* edge_attr   = (const float*)d_in[1];
    const float* global_attr = (const float*)d_in[2];
    const float* node_mask   = (const float*)d_in[3];
    const float* edge_mask   = (const float*)d_in[4];
    const int*   edge_index  = (const int*)d_in[5];
    const int*   eg_index    = (const int*)d_in[6];
    const float* W1          = (const float*)d_in[7];
    const float* b1          = (const float*)d_in[8];
    const float* W2          = (const float*)d_in[9];
    const float* b2          = (const float*)d_in[10];

    ushort_t* W1p = (ushort_t*)d_ws;            // 8*8*64*8 = 32768 elems (64 KB)
    ushort_t* W2p = W1p + 8*8*64*8;             // 4*4*64*8 =  8192 elems (16 KB)

    repack_w<<<20, 256, 0, stream>>>(W1, W2, W1p, W2p);
    edge_mlp<<<N_TILES, 512, 0, stream>>>(
        node_attr, edge_attr, global_attr, node_mask, edge_mask,
        edge_index, eg_index, b1, b2, W1p, W2p, (float*)d_out);
}

// Round 4
// 337.042 us; speedup vs baseline: 2.4932x; 1.2750x over previous
//
#include <hip/hip_runtime.h>
#include <stdint.h>

typedef __attribute__((ext_vector_type(8))) short short8;
typedef __attribute__((ext_vector_type(4))) float floatx4;
typedef unsigned short ushort_t;

#define E_TOTAL 640000
#define N_NODES 20000
#define M_BLK   128
#define N_TILES (E_TOTAL / M_BLK)   // 5000
#define XS_LD   264   // 256 + 8 fp16 pad -> row stride 528B (16B aligned)
#define HS_LD   136   // 128 + 8 fp16 pad -> row stride 272B (16B aligned)

__device__ __forceinline__ unsigned short f2h(float f){
    _Float16 h = (_Float16)f;                  // v_cvt_f16_f32, RNE
    union { _Float16 h; unsigned short u; } v; v.h = h; return v.u;
}
__device__ __forceinline__ unsigned pk2h(float a, float b){
    return (unsigned)f2h(a) | ((unsigned)f2h(b) << 16);
}

// Repack W1[256,128] / W2[128,64] (row-major fp32) into fp16 MFMA B-fragment
// order: lane's 8 B-elements contiguous (one 16B load).
__global__ void repack_w(const float* __restrict__ W1,
                         const float* __restrict__ W2,
                         ushort_t* __restrict__ W1p,
                         ushort_t* __restrict__ W2p){
    int tid = blockIdx.x * 256 + threadIdx.x;
    if (tid < 8*8*64){
        int kt = tid >> 9, nt = (tid >> 6) & 7, l = tid & 63;
        int q = l >> 4, c = l & 15;
        ushort_t tmp[8];
        #pragma unroll
        for (int j = 0; j < 8; j++)
            tmp[j] = f2h(W1[(kt*32 + q*8 + j)*128 + nt*16 + c]);
        #pragma unroll
        for (int j = 0; j < 8; j++) W1p[tid*8 + j] = tmp[j];
    } else if (tid < 8*8*64 + 4*4*64){
        int t = tid - 8*8*64;
        int kt = t >> 8, nt = (t >> 6) & 3, l = t & 63;
        int q = l >> 4, c = l & 15;
        ushort_t tmp[8];
        #pragma unroll
        for (int j = 0; j < 8; j++)
            tmp[j] = f2h(W2[(kt*32 + q*8 + j)*64 + nt*16 + c]);
        #pragma unroll
        for (int j = 0; j < 8; j++) W2p[t*8 + j] = tmp[j];
    }
}

// Pre-masked fp16 node table (2.5 MB, L2-resident) + fp16 global table.
// node16[r][c] = f2h(node_attr[r][c] * node_mask[r])  -- same numerics as
// the in-kernel path (mask applied in fp32, then RNE convert).
__global__ void prep_tables(const float* __restrict__ node_attr,
                            const float* __restrict__ node_mask,
                            const float* __restrict__ global_attr,
                            ushort_t* __restrict__ node16,
                            ushort_t* __restrict__ glob16){
    int gid = blockIdx.x * 256 + threadIdx.x;
    if (gid < N_NODES * 8){                     // 8 elems per thread
        int r = gid >> 3, c8 = gid & 7;
        float m = node_mask[r];
        const float4* src = (const float4*)(node_attr + (size_t)r*64 + c8*8);
        float4 a = src[0], b = src[1];
        uint4 o;
        o.x = pk2h(a.x*m, a.y*m); o.y = pk2h(a.z*m, a.w*m);
        o.z = pk2h(b.x*m, b.y*m); o.w = pk2h(b.z*m, b.w*m);
        *(uint4*)(node16 + (size_t)r*64 + c8*8) = o;
    } else if (gid < N_NODES * 8 + 16 * 8){
        int t = gid - N_NODES * 8;
        int r = t >> 3, c8 = t & 7;
        const float4* src = (const float4*)(global_attr + (size_t)r*64 + c8*8);
        float4 a = src[0], b = src[1];
        uint4 o;
        o.x = pk2h(a.x, a.y); o.y = pk2h(a.z, a.w);
        o.z = pk2h(b.x, b.y); o.w = pk2h(b.z, b.w);
        *(uint4*)(glob16 + (size_t)r*64 + c8*8) = o;
    }
}

// M_BLK=128 baseline structure (proven 173us) + premasked fp16 gathers +
// W1 slice preloaded to registers (GEMM1 inner loop = pure ds_read+MFMA).
__global__ __launch_bounds__(512, 4)
void edge_mlp(const float* __restrict__ edge_attr,
              const float* __restrict__ edge_mask,
              const int*   __restrict__ edge_index,
              const int*   __restrict__ eg_index,
              const float* __restrict__ b1,
              const float* __restrict__ b2,
              const ushort_t* __restrict__ W1p,
              const ushort_t* __restrict__ W2p,
              const ushort_t* __restrict__ node16,
              const ushort_t* __restrict__ glob16,
              float*       __restrict__ out){
    __shared__ ushort_t Xs[M_BLK * XS_LD];   // re-used as Hs after barrier
    ushort_t* Hs = Xs;                        // [M_BLK][HS_LD] overlay

    const int tid = threadIdx.x;
    const int e0  = blockIdx.x * M_BLK;
    const int w   = tid >> 6, lane = tid & 63;
    const int q   = lane >> 4, cc = lane & 15;
    const int mt0 = (w >> 2) * 4;   // GEMM1: wave owns 4mt x 2nt
    const int nt0 = (w & 3) * 2;

    // ---- W1 slice preload (latency overlaps the gather phase) ----
    const short8* W1v = (const short8*)W1p;
    short8 wb[8][2];
    #pragma unroll
    for (int kt = 0; kt < 8; kt++)
        #pragma unroll
        for (int j = 0; j < 2; j++)
            wb[kt][j] = W1v[(kt*8 + nt0 + j)*64 + lane];

    // ---- seg0: edge_attr rows (fp32), coalesced float4, cvt->fp16 ----
    {
        const float4* src = (const float4*)(edge_attr + (size_t)e0 * 64);
        #pragma unroll
        for (int k = 0; k < 4; k++){
            int idx = tid + k*512;            // 0..2047 ; 16 float4 per row
            int r = idx >> 4, c = idx & 15;
            float4 v = src[idx];
            uint2 o; o.x = pk2h(v.x, v.y); o.y = pk2h(v.z, v.w);
            *(uint2*)&Xs[r*XS_LD + c*4] = o;
        }
    }
    // ---- seg3: global gather — fp16 table, pure 16B copies ----
    {
        #pragma unroll
        for (int k = 0; k < 2; k++){
            int idx = tid + k*512;            // 0..1023 ; 8 chunks per row
            int r = idx >> 3, c = idx & 7;
            int g = eg_index[e0 + r];
            uint4 v = *(const uint4*)(glob16 + (size_t)g*64 + c*8);
            *(uint4*)&Xs[r*XS_LD + 192 + c*8] = v;
        }
    }
    // ---- seg1/seg2: node gathers — premasked fp16 table, pure copies ----
    {
        int r = tid >> 2, seg = (tid >> 1) & 1, half = tid & 1;
        int idx = edge_index[seg*E_TOTAL + e0 + r];
        const uint4* nsrc = (const uint4*)(node16 + (size_t)idx*64 + half*32);
        ushort_t* dst = &Xs[r*XS_LD + 64 + seg*64 + half*32];
        #pragma unroll
        for (int c2 = 0; c2 < 4; c2++)
            *(uint4*)(dst + c2*8) = nsrc[c2];
    }
    __syncthreads();

    // ---- GEMM1: H[128,128] = X[128,256] @ W1 ; pure ds_read + MFMA ----
    floatx4 acc[4][2];
    #pragma unroll
    for (int i = 0; i < 4; i++)
        #pragma unroll
        for (int j = 0; j < 2; j++) acc[i][j] = (floatx4){0.f,0.f,0.f,0.f};

    #pragma unroll
    for (int kt = 0; kt < 8; kt++){
        #pragma unroll
        for (int i = 0; i < 4; i++){
            const short8 a = *(const short8*)&Xs[((mt0 + i)*16 + cc)*XS_LD + kt*32 + q*8];
            #pragma unroll
            for (int j = 0; j < 2; j++)
                acc[i][j] = __builtin_amdgcn_mfma_f32_16x16x32_f16(a, wb[kt][j], acc[i][j], 0, 0, 0);
        }
    }
    __syncthreads();   // everyone done reading Xs before Hs overlay

    // ---- epilogue 1: +b1, relu, fp16 -> Hs (row-major) ----
    #pragma unroll
    for (int j = 0; j < 2; j++){
        int col = (nt0 + j)*16 + cc;
        float bb = b1[col];
        #pragma unroll
        for (int i = 0; i < 4; i++){
            int rowb = (mt0 + i)*16 + q*4;
            #pragma unroll
            for (int r = 0; r < 4; r++){
                float v = acc[i][j][r] + bb;
                v = v > 0.f ? v : 0.f;
                Hs[(rowb + r)*HS_LD + col] = f2h(v);
            }
        }
    }
    __syncthreads();

    // ---- GEMM2: OUT[128,64] = H[128,128] @ W2 ; wave owns 2mt x 2nt ----
    const int mt20 = (w >> 1) * 2;  // 0,0,2,2,4,4,6,6
    const int nt20 = (w & 1) * 2;   // 0 or 2

    floatx4 acc2[2][2];
    #pragma unroll
    for (int i = 0; i < 2; i++)
        #pragma unroll
        for (int j = 0; j < 2; j++) acc2[i][j] = (floatx4){0.f,0.f,0.f,0.f};

    const short8* W2v = (const short8*)W2p;
    #pragma unroll
    for (int kt = 0; kt < 4; kt++){
        short8 b[2];
        #pragma unroll
        for (int j = 0; j < 2; j++) b[j] = W2v[(kt*4 + nt20 + j)*64 + lane];
        #pragma unroll
        for (int i = 0; i < 2; i++){
            const short8 a = *(const short8*)&Hs[((mt20 + i)*16 + cc)*HS_LD + kt*32 + q*8];
            #pragma unroll
            for (int j = 0; j < 2; j++)
                acc2[i][j] = __builtin_amdgcn_mfma_f32_16x16x32_f16(a, b[j], acc2[i][j], 0, 0, 0);
        }
    }

    // ---- epilogue 2: +b2, *edge_mask, store fp32 ----
    float bb2[2];
    #pragma unroll
    for (int j = 0; j < 2; j++) bb2[j] = b2[(nt20 + j)*16 + cc];
    #pragma unroll
    for (int i = 0; i < 2; i++){
        #pragma unroll
        for (int r = 0; r < 4; r++){
            int row = (mt20 + i)*16 + q*4 + r;
            float em = edge_mask[e0 + row];
            size_t base = (size_t)(e0 + row) * 64;
            #pragma unroll
            for (int j = 0; j < 2; j++)
                out[base + (nt20 + j)*16 + cc] = (acc2[i][j][r] + bb2[j]) * em;
        }
    }
}

// ---- Fallback: exact 173us baseline (used if workspace too small) ----
__global__ __launch_bounds__(512, 4)
void edge_mlp_fb(const float* __restrict__ node_attr,
                 const float* __restrict__ edge_attr,
                 const float* __restrict__ global_attr,
                 const float* __restrict__ node_mask,
                 const float* __restrict__ edge_mask,
                 const int*   __restrict__ edge_index,
                 const int*   __restrict__ eg_index,
                 const float* __restrict__ b1,
                 const float* __restrict__ b2,
                 const ushort_t* __restrict__ W1p,
                 const ushort_t* __restrict__ W2p,
                 float*       __restrict__ out){
    __shared__ ushort_t Xs[M_BLK * XS_LD];
    ushort_t* Hs = Xs;
    const int tid = threadIdx.x;
    const int e0  = blockIdx.x * M_BLK;
    {
        const float4* src = (const float4*)(edge_attr + (size_t)e0 * 64);
        #pragma unroll
        for (int k = 0; k < 4; k++){
            int idx = tid + k*512;
            int r = idx >> 4, c = idx & 15;
            float4 v = src[idx];
            uint2 o; o.x = pk2h(v.x, v.y); o.y = pk2h(v.z, v.w);
            *(uint2*)&Xs[r*XS_LD + c*4] = o;
        }
    }
    {
        #pragma unroll
        for (int k = 0; k < 4; k++){
            int idx = tid + k*512; int r = idx >> 4, c = idx & 15;
            int g = eg_index[e0 + r];
            const float4* src = (const float4*)(global_attr + (size_t)g * 64);
            float4 v = src[c];
            uint2 o; o.x = pk2h(v.x, v.y); o.y = pk2h(v.z, v.w);
            *(uint2*)&Xs[r*XS_LD + 192 + c*4] = o;
        }
    }
    {
        int r = tid >> 2, seg = (tid >> 1) & 1, half = tid & 1;
        int idx = edge_index[seg*E_TOTAL + e0 + r];
        float m = node_mask[idx];
        const float4* src = (const float4*)(node_attr + (size_t)idx * 64) + half*8;
        ushort_t* dst = &Xs[r*XS_LD + 64 + seg*64 + half*32];
        #pragma unroll
        for (int c2 = 0; c2 < 8; c2++){
            float4 v = src[c2];
            uint2 o; o.x = pk2h(v.x*m, v.y*m); o.y = pk2h(v.z*m, v.w*m);
            *(uint2*)(dst + c2*4) = o;
        }
    }
    __syncthreads();

    const int w  = tid >> 6, lane = tid & 63;
    const int q  = lane >> 4, cc = lane & 15;
    const int mt0 = (w >> 2) * 4;
    const int nt0 = (w & 3) * 2;

    floatx4 acc[4][2];
    #pragma unroll
    for (int i = 0; i < 4; i++)
        #pragma unroll
        for (int j = 0; j < 2; j++) acc[i][j] = (floatx4){0.f,0.f,0.f,0.f};

    const short8* W1v = (const short8*)W1p;
    #pragma unroll
    for (int kt = 0; kt < 8; kt++){
        short8 b[2];
        #pragma unroll
        for (int j = 0; j < 2; j++) b[j] = W1v[(kt*8 + nt0 + j)*64 + lane];
        #pragma unroll
        for (int i = 0; i < 4; i++){
            const short8 a = *(const short8*)&Xs[((mt0 + i)*16 + cc)*XS_LD + kt*32 + q*8];
            #pragma unroll
            for (int j = 0; j < 2; j++)
                acc[i][j] = __builtin_amdgcn_mfma_f32_16x16x32_f16(a, b[j], acc[i][j], 0, 0, 0);
        }
    }
    __syncthreads();

    #pragma unroll
    for (int j = 0; j < 2; j++){
        int col = (nt0 + j)*16 + cc;
        float bb = b1[col];
        #pragma unroll
        for (int i = 0; i < 4; i++){
            int rowb = (mt0 + i)*16 + q*4;
            #pragma unroll
            for (int r = 0; r < 4; r++){
                float v = acc[i][j][r] + bb;
                v = v > 0.f ? v : 0.f;
                Hs[(rowb + r)*HS_LD + col] = f2h(v);
            }
        }
    }
    __syncthreads();

    const int mt20 = (w >> 1) * 2;
    const int nt20 = (w & 1) * 2;

    floatx4 acc2[2][2];
    #pragma unroll
    for (int i = 0; i < 2; i++)
        #pragma unroll
        for (int j = 0; j < 2; j++) acc2[i][j] = (floatx4){0.f,0.f,0.f,0.f};

    const short8* W2v = (const short8*)W2p;
    #pragma unroll
    for (int kt = 0; kt < 4; kt++){
        short8 b[2];
        #pragma unroll
        for (int j = 0; j < 2; j++) b[j] = W2v[(kt*4 + nt20 + j)*64 + lane];
        #pragma unroll
        for (int i = 0; i < 2; i++){
            const short8 a = *(const short8*)&Hs[((mt20 + i)*16 + cc)*HS_LD + kt*32 + q*8];
            #pragma unroll
            for (int j = 0; j < 2; j++)
                acc2[i][j] = __builtin_amdgcn_mfma_f32_16x16x32_f16(a, b[j], acc2[i][j], 0, 0, 0);
        }
    }

    float bb2[2];
    #pragma unroll
    for (int j = 0; j < 2; j++) bb2[j] = b2[(nt20 + j)*16 + cc];
    #pragma unroll
    for (int i = 0; i < 2; i++){
        #pragma unroll
        for (int r = 0; r < 4; r++){
            int row = (mt20 + i)*16 + q*4 + r;
            float em = edge_mask[e0 + row];
            size_t base = (size_t)(e0 + row) * 64;
            #pragma unroll
            for (int j = 0; j < 2; j++)
                out[base + (nt20 + j)*16 + cc] = (acc2[i][j][r] + bb2[j]) * em;
        }
    }
}

extern "C" void kernel_launch(void* const* d_in, const int* in_sizes, int n_in,
                              void* d_out, int out_size, void* d_ws, size_t ws_size,
                              hipStream_t stream){
    const float* node_attr   = (const float*)d_in[0];
    const float* edge_attr   = (const float*)d_in[1];
    const float* global_attr = (const float*)d_in[2];
    const float* node_mask   = (const float*)d_in[3];
    const float* edge_mask   = (const float*)d_in[4];
    const int*   edge_index  = (const int*)d_in[5];
    const int*   eg_index    = (const int*)d_in[6];
    const float* W1          = (const float*)d_in[7];
    const float* b1          = (const float*)d_in[8];
    const float* W2          = (const float*)d_in[9];
    const float* b2          = (const float*)d_in[10];

    ushort_t* W1p = (ushort_t*)d_ws;            // 32768 elems (64 KB)
    ushort_t* W2p = W1p + 8*8*64*8;             //  8192 elems (16 KB)
    ushort_t* node16 = W2p + 4*4*64*8;          // 20000*64 elems (2.5 MB)
    ushort_t* glob16 = node16 + (size_t)N_NODES*64; // 16*64 elems (2 KB)

    size_t need = (size_t)(8*8*64*8 + 4*4*64*8 + N_NODES*64 + 16*64) * sizeof(ushort_t);

    repack_w<<<20, 256, 0, stream>>>(W1, W2, W1p, W2p);
    if (ws_size >= need){
        prep_tables<<<(N_NODES*8 + 16*8 + 255)/256, 256, 0, stream>>>(
            node_attr, node_mask, global_attr, node16, glob16);
        edge_mlp<<<N_TILES, 512, 0, stream>>>(
            edge_attr, edge_mask, edge_index, eg_index,
            b1, b2, W1p, W2p, node16, glob16, (float*)d_out);
    } else {
        edge_mlp_fb<<<N_TILES, 512, 0, stream>>>(
            node_attr, edge_attr, global_attr, node_mask, edge_mask,
            edge_index, eg_index, b1, b2, W1p, W2p, (float*)d_out);
    }
}